// Round 8
// baseline (758.250 us; speedup 1.0000x reference)
//
#include <hip/hip_runtime.h>
#include <hip/hip_bf16.h>
#include <stdint.h>

typedef __attribute__((ext_vector_type(4))) float f32x4;
typedef __attribute__((ext_vector_type(16))) float f32x16;
typedef __attribute__((ext_vector_type(8))) short bf16x8;

#define AS1 __attribute__((address_space(1)))
#define AS3 __attribute__((address_space(3)))

#if defined(__has_builtin)
#if __has_builtin(__builtin_amdgcn_exp2f)
#define EXPF(x) __builtin_amdgcn_exp2f(x)
#define UNITS 1.4426950408889634f
#endif
#endif
#ifndef EXPF
#define EXPF(x) __expf(x)
#define UNITS 1.0f
#endif

static __device__ __forceinline__ unsigned short f2bf(float f) {
  union { float f; unsigned u; } v; v.f = f;
  unsigned r = v.u + 0x7fffu + ((v.u >> 16) & 1u);
  return (unsigned short)(r >> 16);
}

static __device__ __forceinline__ unsigned pkbf(float lo, float hi) {
  __hip_bfloat162 h2 = __float22bfloat162_rn(make_float2(lo, hi));
  union { __hip_bfloat162 h; unsigned u; } c; c.h = h2; return c.u;
}

// ---------------- fused fp32 -> bf16 conversion for all 6 tensors ----------------
__global__ __launch_bounds__(256) void conv_all(
    const float* __restrict__ q, const float* __restrict__ k, const float* __restrict__ v,
    const float* __restrict__ wq, const float* __restrict__ wk, const float* __restrict__ wv,
    unsigned short* __restrict__ Xq, unsigned short* __restrict__ Xk, unsigned short* __restrict__ Xv,
    unsigned short* __restrict__ Wq, unsigned short* __restrict__ Wk, unsigned short* __restrict__ Wv) {
  int bid = blockIdx.x;
  const float* src; unsigned short* dst; int base;
  if (bid < 12288) {
    int t = bid >> 12;
    base = (bid & 4095) * 2048;
    if (t == 0) { src = q; dst = Xq; }
    else if (t == 1) { src = k; dst = Xk; }
    else { src = v; dst = Xv; }
  } else {
    int r = bid - 12288;
    int t = r >> 9;
    base = (r & 511) * 2048;
    if (t == 0) { src = wq; dst = Wq; }
    else if (t == 1) { src = wk; dst = Wk; }
    else { src = wv; dst = Wv; }
  }
  int i = base + threadIdx.x * 8;
  float4 x0 = *(const float4*)(src + i);
  float4 x1 = *(const float4*)(src + i + 4);
  ushort4 o0, o1;
  o0.x = f2bf(x0.x); o0.y = f2bf(x0.y); o0.z = f2bf(x0.z); o0.w = f2bf(x0.w);
  o1.x = f2bf(x1.x); o1.y = f2bf(x1.y); o1.z = f2bf(x1.z); o1.w = f2bf(x1.w);
  *(ushort4*)(dst + i) = o0;
  *(ushort4*)(dst + i + 4) = o1;
}

// ---------------- merged QKV projection GEMM, v2: 2-phase double-buffered staging ----------------
// T3-minimum recipe: stage(k+1) issued BEFORE compute(k); ONE vmcnt(0)+barrier
// (__syncthreads) per K-step. LDS 2x(8KB A + 8KB B) = 32 KB.
__global__ __launch_bounds__(256) void proj_gemm3(
    const unsigned short* __restrict__ Xq, const unsigned short* __restrict__ Xk,
    const unsigned short* __restrict__ Xv,
    const unsigned short* __restrict__ Wqp, const unsigned short* __restrict__ Wkp,
    const unsigned short* __restrict__ Wvp,
    const float* __restrict__ bq, const float* __restrict__ bk, const float* __restrict__ bv,
    unsigned short* __restrict__ Qh, unsigned short* __restrict__ Kh,
    unsigned short* __restrict__ Vt) {
  const int K = 1024, S = 2048, H = 16;
  int z = blockIdx.z;
  const unsigned short *A, *W; const float* bias; unsigned short* dst; int transpose_v;
  if (z == 0)      { A = Xq; W = Wqp; bias = bq; dst = Qh; transpose_v = 0; }
  else if (z == 1) { A = Xk; W = Wkp; bias = bk; dst = Kh; transpose_v = 0; }
  else             { A = Xv; W = Wvp; bias = bv; dst = Vt; transpose_v = 1; }

  __shared__ unsigned short As[2][128 * 32];
  __shared__ unsigned short Bs[2][128 * 32];
  const int tid = threadIdx.x;
  const int l = tid & 63;
  const int w = tid >> 6;
  const int m0 = blockIdx.x * 128, n0 = blockIdx.y * 128;
  const int wm = w >> 1, wn = w & 1;

  f32x4 acc[4][4] = {};

  const int srow = (l >> 2);
  const int skc = (l & 3) * 8;

#define STAGE(buf, k0)                                                            \
  {                                                                               \
    _Pragma("unroll")                                                             \
    for (int i = 0; i < 2; ++i) {                                                 \
      int slot = w * 2 + i;                                                       \
      int row = slot * 16 + srow;                                                 \
      const unsigned short* ga = A + (long)(m0 + row) * K + (k0) + skc;           \
      const unsigned short* gb = W + (long)(n0 + row) * K + (k0) + skc;           \
      __builtin_amdgcn_global_load_lds((const AS1 unsigned int*)ga,               \
                                       (AS3 unsigned int*)(As[buf] + slot * 512 + l * 8), \
                                       16, 0, 0);                                 \
      __builtin_amdgcn_global_load_lds((const AS1 unsigned int*)gb,               \
                                       (AS3 unsigned int*)(Bs[buf] + slot * 512 + l * 8), \
                                       16, 0, 0);                                 \
    }                                                                             \
  }

  STAGE(0, 0);
  __syncthreads();

  int cur = 0;
  for (int k0 = 0; k0 < K; k0 += 32) {
    if (k0 + 32 < K) STAGE(cur ^ 1, k0 + 32);

    bf16x8 af[4], bfr[4];
    const int kc = (l >> 4) * 8;
#pragma unroll
    for (int mi = 0; mi < 4; ++mi)
      af[mi] = *(const bf16x8*)&As[cur][(wm * 64 + mi * 16 + (l & 15)) * 32 + kc];
#pragma unroll
    for (int ni = 0; ni < 4; ++ni)
      bfr[ni] = *(const bf16x8*)&Bs[cur][(wn * 64 + ni * 16 + (l & 15)) * 32 + kc];
#pragma unroll
    for (int mi = 0; mi < 4; ++mi)
#pragma unroll
      for (int ni = 0; ni < 4; ++ni)
        acc[mi][ni] = __builtin_amdgcn_mfma_f32_16x16x32_bf16(af[mi], bfr[ni], acc[mi][ni], 0, 0, 0);

    __syncthreads();  // drains stage(k+1) vmcnt + guards buf reuse
    cur ^= 1;
  }
#undef STAGE

#pragma unroll
  for (int ni = 0; ni < 4; ++ni) {
    int col = n0 + wn * 64 + ni * 16 + (l & 15);
    float bv_ = bias[col];
    int h = col >> 6, dh = col & 63;
#pragma unroll
    for (int mi = 0; mi < 4; ++mi) {
#pragma unroll
      for (int r = 0; r < 4; ++r) {
        int m = m0 + wm * 64 + mi * 16 + (l >> 4) * 4 + r;
        int b = m >> 11, s = m & 2047;
        unsigned short obf = f2bf(acc[mi][ni][r] + bv_);
        long addr;
        if (!transpose_v)
          addr = ((long)(b * H + h) * S + s) * 64 + dh;
        else
          addr = ((long)(b * H + h) * 64 + dh) * S + s;
        dst[addr] = obf;
      }
    }
  }
}

// ---------------- flash attention v5: 4 waves/block, 1024 blocks (occupancy) ----------------
// 4 waves x 32 q-rows (128 q/block), KVBLK=64, 32x32 MFMA, swapped QK^T,
// in-register softmax (T12/T13/T5). K/V LDS-staged 2-phase (unchanged from v4);
// mask add from L1-broadcast global loads (smask LDS dropped -> 32 KB LDS).
__device__ __forceinline__ void stage_tile(const unsigned short* __restrict__ kb,
                                           const unsigned short* __restrict__ vb,
                                           char* Kb, char* Vb, int kv0, int tid) {
#pragma unroll
  for (int j = 0; j < 2; ++j) {
    int c = tid + j * 256;          // chunk 0..511
    int r = c >> 3;                 // tile row 0..63
    int s = (c & 7) ^ (r & 7);      // inverse-swizzled source slot
    const unsigned short* gk = kb + (kv0 + r) * 64 + s * 8;
    const unsigned short* gv = vb + r * 2048 + kv0 + s * 8;
    __builtin_amdgcn_global_load_lds((const AS1 unsigned int*)gk,
                                     (AS3 unsigned int*)(Kb + c * 16), 16, 0, 0);
    __builtin_amdgcn_global_load_lds((const AS1 unsigned int*)gv,
                                     (AS3 unsigned int*)(Vb + c * 16), 16, 0, 0);
  }
}

__device__ __forceinline__ void compute_tile(const char* Kb, const char* Vb,
                                             const bf16x8 (&qf)[4],
                                             const float* __restrict__ mask_b,
                                             int kv0, int hi, int qc,
                                             f32x16 (&acco)[2], float& m_run, float& lrow) {
  const float kSc = 0.125f * UNITS;
  const float THR = 8.0f * UNITS;
  const float MC = 10000.0f * UNITS;
  const int kx = qc & 7;

  // ---- fragments from swizzled LDS: addr = row*128 + (slot^(row&7))*16 ----
  bf16x8 kf[2][4], vf[2][4];
#pragma unroll
  for (int ks = 0; ks < 2; ++ks)
#pragma unroll
    for (int dc = 0; dc < 4; ++dc)
      kf[ks][dc] = *(const bf16x8*)(Kb + (ks * 32 + qc) * 128 + (((dc * 2 + hi) ^ kx) * 16));
#pragma unroll
  for (int dt = 0; dt < 2; ++dt)
#pragma unroll
    for (int c2 = 0; c2 < 4; ++c2)
      vf[dt][c2] = *(const bf16x8*)(Vb + (dt * 32 + qc) * 128 + (((c2 * 2 + hi) ^ kx) * 16));

  // ---- QK^T (swapped): S^T[k][q] ----
  f32x16 st0 = {}, st1 = {};
  __builtin_amdgcn_s_setprio(1);
#pragma unroll
  for (int dc = 0; dc < 4; ++dc) {
    st0 = __builtin_amdgcn_mfma_f32_32x32x16_bf16(kf[0][dc], qf[dc], st0, 0, 0, 0);
    st1 = __builtin_amdgcn_mfma_f32_32x32x16_bf16(kf[1][dc], qf[dc], st1, 0, 0, 0);
  }
  __builtin_amdgcn_s_setprio(0);

  // ---- mask add from global (same addr across 32 lanes -> L1 broadcast) ----
  float mf[2][16];
#pragma unroll
  for (int ks = 0; ks < 2; ++ks)
#pragma unroll
    for (int g = 0; g < 4; ++g) {
      float4 t = *(const float4*)&mask_b[kv0 + ks * 32 + 4 * hi + g * 8];
      mf[ks][g * 4 + 0] = fmaf(t.x, MC, -MC); mf[ks][g * 4 + 1] = fmaf(t.y, MC, -MC);
      mf[ks][g * 4 + 2] = fmaf(t.z, MC, -MC); mf[ks][g * 4 + 3] = fmaf(t.w, MC, -MC);
    }
  float p[2][16];
#pragma unroll
  for (int r = 0; r < 16; ++r) {
    p[0][r] = fmaf(st0[r], kSc, mf[0][r]);
    p[1][r] = fmaf(st1[r], kSc, mf[1][r]);
  }

  float a0 = p[0][0], a1 = p[0][1], a2 = p[0][2], a3 = p[0][3];
#pragma unroll
  for (int r = 4; r < 16; r += 4) {
    a0 = fmaxf(a0, p[0][r]); a1 = fmaxf(a1, p[0][r + 1]);
    a2 = fmaxf(a2, p[0][r + 2]); a3 = fmaxf(a3, p[0][r + 3]);
  }
#pragma unroll
  for (int r = 0; r < 16; r += 4) {
    a0 = fmaxf(a0, p[1][r]); a1 = fmaxf(a1, p[1][r + 1]);
    a2 = fmaxf(a2, p[1][r + 2]); a3 = fmaxf(a3, p[1][r + 3]);
  }
  float pm = fmaxf(fmaxf(a0, a1), fmaxf(a2, a3));
  pm = fmaxf(pm, __shfl_xor(pm, 32));

  if (!__all(pm <= m_run + THR)) {
    float mnew = fmaxf(m_run, pm);
    float scl = EXPF(m_run - mnew);
    lrow *= scl;
#pragma unroll
    for (int dt = 0; dt < 2; ++dt)
#pragma unroll
      for (int r = 0; r < 16; ++r) acco[dt][r] *= scl;
    m_run = mnew;
  }

  float s0 = 0.f, s1 = 0.f, s2 = 0.f, s3 = 0.f;
#pragma unroll
  for (int ks = 0; ks < 2; ++ks)
#pragma unroll
    for (int r = 0; r < 16; r += 4) {
      p[ks][r]     = EXPF(p[ks][r] - m_run);     s0 += p[ks][r];
      p[ks][r + 1] = EXPF(p[ks][r + 1] - m_run); s1 += p[ks][r + 1];
      p[ks][r + 2] = EXPF(p[ks][r + 2] - m_run); s2 += p[ks][r + 2];
      p[ks][r + 3] = EXPF(p[ks][r + 3] - m_run); s3 += p[ks][r + 3];
    }
  float ps = (s0 + s1) + (s2 + s3);
  ps += __shfl_xor(ps, 32);
  lrow += ps;

#pragma unroll
  for (int ks = 0; ks < 2; ++ks) {
    unsigned cp0 = pkbf(p[ks][0], p[ks][1]);
    unsigned cp1 = pkbf(p[ks][2], p[ks][3]);
    unsigned cp2 = pkbf(p[ks][4], p[ks][5]);
    unsigned cp3 = pkbf(p[ks][6], p[ks][7]);
    unsigned cp4 = pkbf(p[ks][8], p[ks][9]);
    unsigned cp5 = pkbf(p[ks][10], p[ks][11]);
    unsigned cp6 = pkbf(p[ks][12], p[ks][13]);
    unsigned cp7 = pkbf(p[ks][14], p[ks][15]);
    asm volatile("v_permlane32_swap_b32 %0, %1" : "+v"(cp0), "+v"(cp2));
    asm volatile("v_permlane32_swap_b32 %0, %1" : "+v"(cp1), "+v"(cp3));
    asm volatile("v_permlane32_swap_b32 %0, %1" : "+v"(cp4), "+v"(cp6));
    asm volatile("v_permlane32_swap_b32 %0, %1" : "+v"(cp5), "+v"(cp7));
    union { unsigned u[4]; bf16x8 v; } B0, B1;
    B0.u[0] = cp0; B0.u[1] = cp1; B0.u[2] = cp2; B0.u[3] = cp3;
    B1.u[0] = cp4; B1.u[1] = cp5; B1.u[2] = cp6; B1.u[3] = cp7;
    __builtin_amdgcn_s_setprio(1);
    acco[0] = __builtin_amdgcn_mfma_f32_32x32x16_bf16(vf[0][ks * 2 + 0], B0.v, acco[0], 0, 0, 0);
    acco[1] = __builtin_amdgcn_mfma_f32_32x32x16_bf16(vf[1][ks * 2 + 0], B0.v, acco[1], 0, 0, 0);
    acco[0] = __builtin_amdgcn_mfma_f32_32x32x16_bf16(vf[0][ks * 2 + 1], B1.v, acco[0], 0, 0, 0);
    acco[1] = __builtin_amdgcn_mfma_f32_32x32x16_bf16(vf[1][ks * 2 + 1], B1.v, acco[1], 0, 0, 0);
    __builtin_amdgcn_s_setprio(0);
  }
}

__global__ __launch_bounds__(256, 4) void attn_kernel(const unsigned short* __restrict__ qh,
                                                      const unsigned short* __restrict__ kh,
                                                      const unsigned short* __restrict__ vt,
                                                      const float* __restrict__ mask,
                                                      float* __restrict__ out) {
  const int S = 2048;
  // XCD swizzle: 1024 blocks; all 16 q-blocks of a bh share an XCD.
  int bid = blockIdx.x;
  int xcd = bid & 7, jj = bid >> 3;
  int bh = xcd * 8 + (jj & 7);
  int qblk = jj >> 3;  // 0..15
  int b = bh >> 4, h = bh & 15;
  int tid = threadIdx.x, l = tid & 63, w = tid >> 6;
  int hi = l >> 5, qc = l & 31;

  const unsigned short* qb = qh + (long)bh * S * 64;
  const unsigned short* kb = kh + (long)bh * S * 64;
  const unsigned short* vb = vt + (long)bh * 64 * S;
  const float* mask_b = mask + (long)b * S;

  // pool: [2][ K(8KB) + V(8KB) ] double buffer = 32 KB; reused as olds[4][16][65] (16.6 KB)
  __shared__ __align__(16) char pool[32768];

  const int q0 = qblk * 128 + w * 32;

  bf16x8 qf[4];
#pragma unroll
  for (int dc = 0; dc < 4; ++dc)
    qf[dc] = *(const bf16x8*)&qb[(q0 + qc) * 64 + dc * 16 + 8 * hi];

  f32x16 acco[2] = {};
  float m_run = -1e30f, lrow = 0.0f;

  // 2-phase pipeline: stage(next) issued before compute(cur); __syncthreads
  // (vmcnt(0)+lgkmcnt(0)+barrier) at tile end — latency hidden under compute.
  stage_tile(kb, vb, pool, pool + 8192, 0, tid);
  __syncthreads();

  for (int t = 0; t < 32; ++t) {
    char* cur = pool + (t & 1) * 16384;
    if (t < 31) {
      char* nxt = pool + ((t + 1) & 1) * 16384;
      stage_tile(kb, vb, nxt, nxt + 8192, (t + 1) * 64, tid);
    }
    compute_tile(cur, cur + 8192, qf, mask_b, t * 64, hi, qc, acco, m_run, lrow);
    __syncthreads();
  }

  // ---- epilogue: normalize, per-wave LDS transpose (pool reused), coalesced stores ----
  float (*olds)[16][65] = (float (*)[16][65])pool;
  float linv = 1.0f / lrow;
#pragma unroll
  for (int pass = 0; pass < 2; ++pass) {
    if ((qc >> 4) == pass) {
#pragma unroll
      for (int dt = 0; dt < 2; ++dt)
#pragma unroll
        for (int r = 0; r < 16; ++r) {
          int d = dt * 32 + (r & 3) + 8 * (r >> 2) + 4 * hi;
          olds[w][qc & 15][d] = acco[dt][r] * linv;
        }
    }
    asm volatile("s_waitcnt lgkmcnt(0)" ::: "memory");
#pragma unroll
    for (int r = 0; r < 16; ++r) {
      float val = olds[w][r][l];
      out[((long)b * 2048 + q0 + pass * 16 + r) * 1024 + h * 64 + l] = val;
    }
    asm volatile("s_waitcnt lgkmcnt(0)" ::: "memory");
  }
}

// ---------------- launch ----------------
extern "C" void kernel_launch(void* const* d_in, const int* in_sizes, int n_in,
                              void* d_out, int out_size, void* d_ws, size_t ws_size,
                              hipStream_t stream) {
  const float* q  = (const float*)d_in[0];
  const float* k  = (const float*)d_in[1];
  const float* v  = (const float*)d_in[2];
  const float* mask = (const float*)d_in[3];
  const float* wq = (const float*)d_in[4];
  const float* bq = (const float*)d_in[5];
  const float* wk = (const float*)d_in[6];
  const float* bk = (const float*)d_in[7];
  const float* wv = (const float*)d_in[8];
  const float* bv = (const float*)d_in[9];
  float* out = (float*)d_out;

  char* ws = (char*)d_ws;
  unsigned short* Xq = (unsigned short*)(ws);
  unsigned short* Xk = (unsigned short*)(ws + 16777216L);
  unsigned short* Xv = (unsigned short*)(ws + 33554432L);
  unsigned short* Wq = (unsigned short*)(ws + 50331648L);
  unsigned short* Wk = (unsigned short*)(ws + 52428800L);
  unsigned short* Wv = (unsigned short*)(ws + 54525952L);
  unsigned short* Qh = (unsigned short*)(ws + 56623104L);
  unsigned short* Kh = (unsigned short*)(ws + 73400320L);
  unsigned short* Vt = (unsigned short*)(ws + 90177536L);

  // 1) fused bf16 conversion (1 launch)
  conv_all<<<13824, 256, 0, stream>>>(q, k, v, wq, wk, wv, Xq, Xk, Xv, Wq, Wk, Wv);

  // 2) merged QKV projections (1 launch, 2-phase pipelined)
  dim3 ggrid(64, 8, 3);
  proj_gemm3<<<ggrid, 256, 0, stream>>>(Xq, Xk, Xv, Wq, Wk, Wv, bq, bk, bv, Qh, Kh, Vt);

  // 3) flash attention + head merge (1 launch, 1024 blocks)
  attn_kernel<<<1024, 256, 0, stream>>>(Qh, Kh, Vt, mask, out);
}

// Round 10
// 377.309 us; speedup vs baseline: 2.0096x; 2.0096x over previous
//
#include <hip/hip_runtime.h>
#include <hip/hip_bf16.h>
#include <stdint.h>

typedef __attribute__((ext_vector_type(4))) float f32x4;
typedef __attribute__((ext_vector_type(16))) float f32x16;
typedef __attribute__((ext_vector_type(8))) short bf16x8;

#define AS1 __attribute__((address_space(1)))
#define AS3 __attribute__((address_space(3)))

#if defined(__has_builtin)
#if __has_builtin(__builtin_amdgcn_exp2f)
#define EXPF(x) __builtin_amdgcn_exp2f(x)
#define UNITS 1.4426950408889634f
#endif
#endif
#ifndef EXPF
#define EXPF(x) __expf(x)
#define UNITS 1.0f
#endif

static __device__ __forceinline__ unsigned short f2bf(float f) {
  union { float f; unsigned u; } v; v.f = f;
  unsigned r = v.u + 0x7fffu + ((v.u >> 16) & 1u);
  return (unsigned short)(r >> 16);
}

static __device__ __forceinline__ unsigned pkbf(float lo, float hi) {
  __hip_bfloat162 h2 = __float22bfloat162_rn(make_float2(lo, hi));
  union { __hip_bfloat162 h; unsigned u; } c; c.h = h2; return c.u;
}

// ---------------- fused fp32 -> bf16 conversion for all 6 tensors ----------------
__global__ __launch_bounds__(256) void conv_all(
    const float* __restrict__ q, const float* __restrict__ k, const float* __restrict__ v,
    const float* __restrict__ wq, const float* __restrict__ wk, const float* __restrict__ wv,
    unsigned short* __restrict__ Xq, unsigned short* __restrict__ Xk, unsigned short* __restrict__ Xv,
    unsigned short* __restrict__ Wq, unsigned short* __restrict__ Wk, unsigned short* __restrict__ Wv) {
  int bid = blockIdx.x;
  const float* src; unsigned short* dst; int base;
  if (bid < 12288) {
    int t = bid >> 12;
    base = (bid & 4095) * 2048;
    if (t == 0) { src = q; dst = Xq; }
    else if (t == 1) { src = k; dst = Xk; }
    else { src = v; dst = Xv; }
  } else {
    int r = bid - 12288;
    int t = r >> 9;
    base = (r & 511) * 2048;
    if (t == 0) { src = wq; dst = Wq; }
    else if (t == 1) { src = wk; dst = Wk; }
    else { src = wv; dst = Wv; }
  }
  int i = base + threadIdx.x * 8;
  float4 x0 = *(const float4*)(src + i);
  float4 x1 = *(const float4*)(src + i + 4);
  ushort4 o0, o1;
  o0.x = f2bf(x0.x); o0.y = f2bf(x0.y); o0.z = f2bf(x0.z); o0.w = f2bf(x0.w);
  o1.x = f2bf(x1.x); o1.y = f2bf(x1.y); o1.z = f2bf(x1.z); o1.w = f2bf(x1.w);
  *(ushort4*)(dst + i) = o0;
  *(ushort4*)(dst + i + 4) = o1;
}

// ---------------- merged QKV projection GEMM, v2: 2-phase double-buffered staging ----------------
__global__ __launch_bounds__(256) void proj_gemm3(
    const unsigned short* __restrict__ Xq, const unsigned short* __restrict__ Xk,
    const unsigned short* __restrict__ Xv,
    const unsigned short* __restrict__ Wqp, const unsigned short* __restrict__ Wkp,
    const unsigned short* __restrict__ Wvp,
    const float* __restrict__ bq, const float* __restrict__ bk, const float* __restrict__ bv,
    unsigned short* __restrict__ Qh, unsigned short* __restrict__ Kh,
    unsigned short* __restrict__ Vt) {
  const int K = 1024, S = 2048, H = 16;
  int z = blockIdx.z;
  const unsigned short *A, *W; const float* bias; unsigned short* dst; int transpose_v;
  if (z == 0)      { A = Xq; W = Wqp; bias = bq; dst = Qh; transpose_v = 0; }
  else if (z == 1) { A = Xk; W = Wkp; bias = bk; dst = Kh; transpose_v = 0; }
  else             { A = Xv; W = Wvp; bias = bv; dst = Vt; transpose_v = 1; }

  __shared__ unsigned short As[2][128 * 32];
  __shared__ unsigned short Bs[2][128 * 32];
  const int tid = threadIdx.x;
  const int l = tid & 63;
  const int w = tid >> 6;
  const int m0 = blockIdx.x * 128, n0 = blockIdx.y * 128;
  const int wm = w >> 1, wn = w & 1;

  f32x4 acc[4][4] = {};

  const int srow = (l >> 2);
  const int skc = (l & 3) * 8;

#define STAGE(buf, k0)                                                            \
  {                                                                               \
    _Pragma("unroll")                                                             \
    for (int i = 0; i < 2; ++i) {                                                 \
      int slot = w * 2 + i;                                                       \
      int row = slot * 16 + srow;                                                 \
      const unsigned short* ga = A + (long)(m0 + row) * K + (k0) + skc;           \
      const unsigned short* gb = W + (long)(n0 + row) * K + (k0) + skc;           \
      __builtin_amdgcn_global_load_lds((const AS1 unsigned int*)ga,               \
                                       (AS3 unsigned int*)(As[buf] + slot * 512 + l * 8), \
                                       16, 0, 0);                                 \
      __builtin_amdgcn_global_load_lds((const AS1 unsigned int*)gb,               \
                                       (AS3 unsigned int*)(Bs[buf] + slot * 512 + l * 8), \
                                       16, 0, 0);                                 \
    }                                                                             \
  }

  STAGE(0, 0);
  __syncthreads();

  int cur = 0;
  for (int k0 = 0; k0 < K; k0 += 32) {
    if (k0 + 32 < K) STAGE(cur ^ 1, k0 + 32);

    bf16x8 af[4], bfr[4];
    const int kc = (l >> 4) * 8;
#pragma unroll
    for (int mi = 0; mi < 4; ++mi)
      af[mi] = *(const bf16x8*)&As[cur][(wm * 64 + mi * 16 + (l & 15)) * 32 + kc];
#pragma unroll
    for (int ni = 0; ni < 4; ++ni)
      bfr[ni] = *(const bf16x8*)&Bs[cur][(wn * 64 + ni * 16 + (l & 15)) * 32 + kc];
#pragma unroll
    for (int mi = 0; mi < 4; ++mi)
#pragma unroll
      for (int ni = 0; ni < 4; ++ni)
        acc[mi][ni] = __builtin_amdgcn_mfma_f32_16x16x32_bf16(af[mi], bfr[ni], acc[mi][ni], 0, 0, 0);

    __syncthreads();  // drains stage(k+1) vmcnt + guards buf reuse
    cur ^= 1;
  }
#undef STAGE

#pragma unroll
  for (int ni = 0; ni < 4; ++ni) {
    int col = n0 + wn * 64 + ni * 16 + (l & 15);
    float bv_ = bias[col];
    int h = col >> 6, dh = col & 63;
#pragma unroll
    for (int mi = 0; mi < 4; ++mi) {
#pragma unroll
      for (int r = 0; r < 4; ++r) {
        int m = m0 + wm * 64 + mi * 16 + (l >> 4) * 4 + r;
        int b = m >> 11, s = m & 2047;
        unsigned short obf = f2bf(acc[mi][ni][r] + bv_);
        long addr;
        if (!transpose_v)
          addr = ((long)(b * H + h) * S + s) * 64 + dh;
        else
          addr = ((long)(b * H + h) * 64 + dh) * S + s;
        dst[addr] = obf;
      }
    }
  }
}

// ---------------- flash attention v5b: 4 waves/block, 1024 blocks, NO reg cap ----------------
// Identical to v5 except __launch_bounds__(256) — round 8's (256,4) forced a
// ~128 unified-VGPR cap and spilled the accumulators (982 MB scratch writes).
__device__ __forceinline__ void stage_tile(const unsigned short* __restrict__ kb,
                                           const unsigned short* __restrict__ vb,
                                           char* Kb, char* Vb, int kv0, int tid) {
#pragma unroll
  for (int j = 0; j < 2; ++j) {
    int c = tid + j * 256;          // chunk 0..511
    int r = c >> 3;                 // tile row 0..63
    int s = (c & 7) ^ (r & 7);      // inverse-swizzled source slot
    const unsigned short* gk = kb + (kv0 + r) * 64 + s * 8;
    const unsigned short* gv = vb + r * 2048 + kv0 + s * 8;
    __builtin_amdgcn_global_load_lds((const AS1 unsigned int*)gk,
                                     (AS3 unsigned int*)(Kb + c * 16), 16, 0, 0);
    __builtin_amdgcn_global_load_lds((const AS1 unsigned int*)gv,
                                     (AS3 unsigned int*)(Vb + c * 16), 16, 0, 0);
  }
}

__device__ __forceinline__ void compute_tile(const char* Kb, const char* Vb,
                                             const bf16x8 (&qf)[4],
                                             const float* __restrict__ mask_b,
                                             int kv0, int hi, int qc,
                                             f32x16 (&acco)[2], float& m_run, float& lrow) {
  const float kSc = 0.125f * UNITS;
  const float THR = 8.0f * UNITS;
  const float MC = 10000.0f * UNITS;
  const int kx = qc & 7;

  bf16x8 kf[2][4], vf[2][4];
#pragma unroll
  for (int ks = 0; ks < 2; ++ks)
#pragma unroll
    for (int dc = 0; dc < 4; ++dc)
      kf[ks][dc] = *(const bf16x8*)(Kb + (ks * 32 + qc) * 128 + (((dc * 2 + hi) ^ kx) * 16));
#pragma unroll
  for (int dt = 0; dt < 2; ++dt)
#pragma unroll
    for (int c2 = 0; c2 < 4; ++c2)
      vf[dt][c2] = *(const bf16x8*)(Vb + (dt * 32 + qc) * 128 + (((c2 * 2 + hi) ^ kx) * 16));

  f32x16 st0 = {}, st1 = {};
  __builtin_amdgcn_s_setprio(1);
#pragma unroll
  for (int dc = 0; dc < 4; ++dc) {
    st0 = __builtin_amdgcn_mfma_f32_32x32x16_bf16(kf[0][dc], qf[dc], st0, 0, 0, 0);
    st1 = __builtin_amdgcn_mfma_f32_32x32x16_bf16(kf[1][dc], qf[dc], st1, 0, 0, 0);
  }
  __builtin_amdgcn_s_setprio(0);

  float mf[2][16];
#pragma unroll
  for (int ks = 0; ks < 2; ++ks)
#pragma unroll
    for (int g = 0; g < 4; ++g) {
      float4 t = *(const float4*)&mask_b[kv0 + ks * 32 + 4 * hi + g * 8];
      mf[ks][g * 4 + 0] = fmaf(t.x, MC, -MC); mf[ks][g * 4 + 1] = fmaf(t.y, MC, -MC);
      mf[ks][g * 4 + 2] = fmaf(t.z, MC, -MC); mf[ks][g * 4 + 3] = fmaf(t.w, MC, -MC);
    }
  float p[2][16];
#pragma unroll
  for (int r = 0; r < 16; ++r) {
    p[0][r] = fmaf(st0[r], kSc, mf[0][r]);
    p[1][r] = fmaf(st1[r], kSc, mf[1][r]);
  }

  float a0 = p[0][0], a1 = p[0][1], a2 = p[0][2], a3 = p[0][3];
#pragma unroll
  for (int r = 4; r < 16; r += 4) {
    a0 = fmaxf(a0, p[0][r]); a1 = fmaxf(a1, p[0][r + 1]);
    a2 = fmaxf(a2, p[0][r + 2]); a3 = fmaxf(a3, p[0][r + 3]);
  }
#pragma unroll
  for (int r = 0; r < 16; r += 4) {
    a0 = fmaxf(a0, p[1][r]); a1 = fmaxf(a1, p[1][r + 1]);
    a2 = fmaxf(a2, p[1][r + 2]); a3 = fmaxf(a3, p[1][r + 3]);
  }
  float pm = fmaxf(fmaxf(a0, a1), fmaxf(a2, a3));
  pm = fmaxf(pm, __shfl_xor(pm, 32));

  if (!__all(pm <= m_run + THR)) {
    float mnew = fmaxf(m_run, pm);
    float scl = EXPF(m_run - mnew);
    lrow *= scl;
#pragma unroll
    for (int dt = 0; dt < 2; ++dt)
#pragma unroll
      for (int r = 0; r < 16; ++r) acco[dt][r] *= scl;
    m_run = mnew;
  }

  float s0 = 0.f, s1 = 0.f, s2 = 0.f, s3 = 0.f;
#pragma unroll
  for (int ks = 0; ks < 2; ++ks)
#pragma unroll
    for (int r = 0; r < 16; r += 4) {
      p[ks][r]     = EXPF(p[ks][r] - m_run);     s0 += p[ks][r];
      p[ks][r + 1] = EXPF(p[ks][r + 1] - m_run); s1 += p[ks][r + 1];
      p[ks][r + 2] = EXPF(p[ks][r + 2] - m_run); s2 += p[ks][r + 2];
      p[ks][r + 3] = EXPF(p[ks][r + 3] - m_run); s3 += p[ks][r + 3];
    }
  float ps = (s0 + s1) + (s2 + s3);
  ps += __shfl_xor(ps, 32);
  lrow += ps;

#pragma unroll
  for (int ks = 0; ks < 2; ++ks) {
    unsigned cp0 = pkbf(p[ks][0], p[ks][1]);
    unsigned cp1 = pkbf(p[ks][2], p[ks][3]);
    unsigned cp2 = pkbf(p[ks][4], p[ks][5]);
    unsigned cp3 = pkbf(p[ks][6], p[ks][7]);
    unsigned cp4 = pkbf(p[ks][8], p[ks][9]);
    unsigned cp5 = pkbf(p[ks][10], p[ks][11]);
    unsigned cp6 = pkbf(p[ks][12], p[ks][13]);
    unsigned cp7 = pkbf(p[ks][14], p[ks][15]);
    asm volatile("v_permlane32_swap_b32 %0, %1" : "+v"(cp0), "+v"(cp2));
    asm volatile("v_permlane32_swap_b32 %0, %1" : "+v"(cp1), "+v"(cp3));
    asm volatile("v_permlane32_swap_b32 %0, %1" : "+v"(cp4), "+v"(cp6));
    asm volatile("v_permlane32_swap_b32 %0, %1" : "+v"(cp5), "+v"(cp7));
    union { unsigned u[4]; bf16x8 v; } B0, B1;
    B0.u[0] = cp0; B0.u[1] = cp1; B0.u[2] = cp2; B0.u[3] = cp3;
    B1.u[0] = cp4; B1.u[1] = cp5; B1.u[2] = cp6; B1.u[3] = cp7;
    __builtin_amdgcn_s_setprio(1);
    acco[0] = __builtin_amdgcn_mfma_f32_32x32x16_bf16(vf[0][ks * 2 + 0], B0.v, acco[0], 0, 0, 0);
    acco[1] = __builtin_amdgcn_mfma_f32_32x32x16_bf16(vf[1][ks * 2 + 0], B0.v, acco[1], 0, 0, 0);
    acco[0] = __builtin_amdgcn_mfma_f32_32x32x16_bf16(vf[0][ks * 2 + 1], B1.v, acco[0], 0, 0, 0);
    acco[1] = __builtin_amdgcn_mfma_f32_32x32x16_bf16(vf[1][ks * 2 + 1], B1.v, acco[1], 0, 0, 0);
    __builtin_amdgcn_s_setprio(0);
  }
}

__global__ __launch_bounds__(256) void attn_kernel(const unsigned short* __restrict__ qh,
                                                   const unsigned short* __restrict__ kh,
                                                   const unsigned short* __restrict__ vt,
                                                   const float* __restrict__ mask,
                                                   float* __restrict__ out) {
  const int S = 2048;
  // XCD swizzle: 1024 blocks; all 16 q-blocks of a bh share an XCD.
  int bid = blockIdx.x;
  int xcd = bid & 7, jj = bid >> 3;
  int bh = xcd * 8 + (jj & 7);
  int qblk = jj >> 3;  // 0..15
  int b = bh >> 4, h = bh & 15;
  int tid = threadIdx.x, l = tid & 63, w = tid >> 6;
  int hi = l >> 5, qc = l & 31;

  const unsigned short* qb = qh + (long)bh * S * 64;
  const unsigned short* kb = kh + (long)bh * S * 64;
  const unsigned short* vb = vt + (long)bh * 64 * S;
  const float* mask_b = mask + (long)b * S;

  // pool: [2][ K(8KB) + V(8KB) ] double buffer = 32 KB; reused as olds[4][16][65] (16.6 KB)
  __shared__ __align__(16) char pool[32768];

  const int q0 = qblk * 128 + w * 32;

  bf16x8 qf[4];
#pragma unroll
  for (int dc = 0; dc < 4; ++dc)
    qf[dc] = *(const bf16x8*)&qb[(q0 + qc) * 64 + dc * 16 + 8 * hi];

  f32x16 acco[2] = {};
  float m_run = -1e30f, lrow = 0.0f;

  stage_tile(kb, vb, pool, pool + 8192, 0, tid);
  __syncthreads();

  for (int t = 0; t < 32; ++t) {
    char* cur = pool + (t & 1) * 16384;
    if (t < 31) {
      char* nxt = pool + ((t + 1) & 1) * 16384;
      stage_tile(kb, vb, nxt, nxt + 8192, (t + 1) * 64, tid);
    }
    compute_tile(cur, cur + 8192, qf, mask_b, t * 64, hi, qc, acco, m_run, lrow);
    __syncthreads();
  }

  // ---- epilogue: normalize, per-wave LDS transpose (pool reused), coalesced stores ----
  float (*olds)[16][65] = (float (*)[16][65])pool;
  float linv = 1.0f / lrow;
#pragma unroll
  for (int pass = 0; pass < 2; ++pass) {
    if ((qc >> 4) == pass) {
#pragma unroll
      for (int dt = 0; dt < 2; ++dt)
#pragma unroll
        for (int r = 0; r < 16; ++r) {
          int d = dt * 32 + (r & 3) + 8 * (r >> 2) + 4 * hi;
          olds[w][qc & 15][d] = acco[dt][r] * linv;
        }
    }
    asm volatile("s_waitcnt lgkmcnt(0)" ::: "memory");
#pragma unroll
    for (int r = 0; r < 16; ++r) {
      float val = olds[w][r][l];
      out[((long)b * 2048 + q0 + pass * 16 + r) * 1024 + h * 64 + l] = val;
    }
    asm volatile("s_waitcnt lgkmcnt(0)" ::: "memory");
  }
}

// ---------------- launch ----------------
extern "C" void kernel_launch(void* const* d_in, const int* in_sizes, int n_in,
                              void* d_out, int out_size, void* d_ws, size_t ws_size,
                              hipStream_t stream) {
  const float* q  = (const float*)d_in[0];
  const float* k  = (const float*)d_in[1];
  const float* v  = (const float*)d_in[2];
  const float* mask = (const float*)d_in[3];
  const float* wq = (const float*)d_in[4];
  const float* bq = (const float*)d_in[5];
  const float* wk = (const float*)d_in[6];
  const float* bk = (const float*)d_in[7];
  const float* wv = (const float*)d_in[8];
  const float* bv = (const float*)d_in[9];
  float* out = (float*)d_out;

  char* ws = (char*)d_ws;
  unsigned short* Xq = (unsigned short*)(ws);
  unsigned short* Xk = (unsigned short*)(ws + 16777216L);
  unsigned short* Xv = (unsigned short*)(ws + 33554432L);
  unsigned short* Wq = (unsigned short*)(ws + 50331648L);
  unsigned short* Wk = (unsigned short*)(ws + 52428800L);
  unsigned short* Wv = (unsigned short*)(ws + 54525952L);
  unsigned short* Qh = (unsigned short*)(ws + 56623104L);
  unsigned short* Kh = (unsigned short*)(ws + 73400320L);
  unsigned short* Vt = (unsigned short*)(ws + 90177536L);

  // 1) fused bf16 conversion (1 launch)
  conv_all<<<13824, 256, 0, stream>>>(q, k, v, wq, wk, wv, Xq, Xk, Xv, Wq, Wk, Wv);

  // 2) merged QKV projections (1 launch, 2-phase pipelined)
  dim3 ggrid(64, 8, 3);
  proj_gemm3<<<ggrid, 256, 0, stream>>>(Xq, Xk, Xv, Wq, Wk, Wv, bq, bk, bv, Qh, Kh, Vt);

  // 3) flash attention + head merge (1 launch, 1024 blocks)
  attn_kernel<<<1024, 256, 0, stream>>>(Qh, Kh, Vt, mask, out);
}

// Round 12
// 356.860 us; speedup vs baseline: 2.1248x; 1.0573x over previous
//
#include <hip/hip_runtime.h>
#include <hip/hip_bf16.h>
#include <stdint.h>

typedef __attribute__((ext_vector_type(4))) float f32x4;
typedef __attribute__((ext_vector_type(16))) float f32x16;
typedef __attribute__((ext_vector_type(8))) short bf16x8;

#define AS1 __attribute__((address_space(1)))
#define AS3 __attribute__((address_space(3)))

#if defined(__has_builtin)
#if __has_builtin(__builtin_amdgcn_exp2f)
#define EXPF(x) __builtin_amdgcn_exp2f(x)
#define UNITS 1.4426950408889634f
#endif
#endif
#ifndef EXPF
#define EXPF(x) __expf(x)
#define UNITS 1.0f
#endif

static __device__ __forceinline__ unsigned short f2bf(float f) {
  union { float f; unsigned u; } v; v.f = f;
  unsigned r = v.u + 0x7fffu + ((v.u >> 16) & 1u);
  return (unsigned short)(r >> 16);
}

static __device__ __forceinline__ unsigned pkbf(float lo, float hi) {
  __hip_bfloat162 h2 = __float22bfloat162_rn(make_float2(lo, hi));
  union { __hip_bfloat162 h; unsigned u; } c; c.h = h2; return c.u;
}

// ---------------- fused fp32 -> bf16 conversion for all 6 tensors ----------------
__global__ __launch_bounds__(256) void conv_all(
    const float* __restrict__ q, const float* __restrict__ k, const float* __restrict__ v,
    const float* __restrict__ wq, const float* __restrict__ wk, const float* __restrict__ wv,
    unsigned short* __restrict__ Xq, unsigned short* __restrict__ Xk, unsigned short* __restrict__ Xv,
    unsigned short* __restrict__ Wq, unsigned short* __restrict__ Wk, unsigned short* __restrict__ Wv) {
  int bid = blockIdx.x;
  const float* src; unsigned short* dst; int base;
  if (bid < 12288) {
    int t = bid >> 12;
    base = (bid & 4095) * 2048;
    if (t == 0) { src = q; dst = Xq; }
    else if (t == 1) { src = k; dst = Xk; }
    else { src = v; dst = Xv; }
  } else {
    int r = bid - 12288;
    int t = r >> 9;
    base = (r & 511) * 2048;
    if (t == 0) { src = wq; dst = Wq; }
    else if (t == 1) { src = wk; dst = Wk; }
    else { src = wv; dst = Wv; }
  }
  int i = base + threadIdx.x * 8;
  float4 x0 = *(const float4*)(src + i);
  float4 x1 = *(const float4*)(src + i + 4);
  ushort4 o0, o1;
  o0.x = f2bf(x0.x); o0.y = f2bf(x0.y); o0.z = f2bf(x0.z); o0.w = f2bf(x0.w);
  o1.x = f2bf(x1.x); o1.y = f2bf(x1.y); o1.z = f2bf(x1.z); o1.w = f2bf(x1.w);
  *(ushort4*)(dst + i) = o0;
  *(ushort4*)(dst + i + 4) = o1;
}

// ---------------- merged QKV projection GEMM v3: 8 waves, low-reg, 2-phase ----------------
// 128x128 tile, BK=32, 8 waves (2x4 wave grid), per-wave acc 4x2 (32 AGPR).
// One A+B gload pair per thread per K-step; stage(k+1) before compute(k).
__global__ __launch_bounds__(512) void proj_gemm3(
    const unsigned short* __restrict__ Xq, const unsigned short* __restrict__ Xk,
    const unsigned short* __restrict__ Xv,
    const unsigned short* __restrict__ Wqp, const unsigned short* __restrict__ Wkp,
    const unsigned short* __restrict__ Wvp,
    const float* __restrict__ bq, const float* __restrict__ bk, const float* __restrict__ bv,
    unsigned short* __restrict__ Qh, unsigned short* __restrict__ Kh,
    unsigned short* __restrict__ Vt) {
  const int K = 1024, S = 2048, H = 16;
  int z = blockIdx.z;
  const unsigned short *A, *W; const float* bias; unsigned short* dst; int transpose_v;
  if (z == 0)      { A = Xq; W = Wqp; bias = bq; dst = Qh; transpose_v = 0; }
  else if (z == 1) { A = Xk; W = Wkp; bias = bk; dst = Kh; transpose_v = 0; }
  else             { A = Xv; W = Wvp; bias = bv; dst = Vt; transpose_v = 1; }

  __shared__ unsigned short As[2][128 * 32];
  __shared__ unsigned short Bs[2][128 * 32];
  const int tid = threadIdx.x;      // 0..511
  const int l = tid & 63;
  const int w = tid >> 6;           // 0..7
  const int m0 = blockIdx.x * 128, n0 = blockIdx.y * 128;
  const int wm = w >> 2, wn = w & 3;

  f32x4 acc[4][2] = {};

  const int srow = tid >> 2;        // 0..127
  const int scol = (tid & 3) * 8;   // k offset 0,8,16,24

#define STAGE(buf, k0)                                                            \
  {                                                                               \
    const unsigned short* ga = A + (long)(m0 + srow) * K + (k0) + scol;           \
    const unsigned short* gb = W + (long)(n0 + srow) * K + (k0) + scol;           \
    __builtin_amdgcn_global_load_lds((const AS1 unsigned int*)ga,                 \
                                     (AS3 unsigned int*)(As[buf] + tid * 8),      \
                                     16, 0, 0);                                   \
    __builtin_amdgcn_global_load_lds((const AS1 unsigned int*)gb,                 \
                                     (AS3 unsigned int*)(Bs[buf] + tid * 8),      \
                                     16, 0, 0);                                   \
  }

  STAGE(0, 0);
  __syncthreads();

  int cur = 0;
  for (int k0 = 0; k0 < K; k0 += 32) {
    if (k0 + 32 < K) STAGE(cur ^ 1, k0 + 32);

    bf16x8 af[4], bfr[2];
    const int kc = (l >> 4) * 8;
#pragma unroll
    for (int mi = 0; mi < 4; ++mi)
      af[mi] = *(const bf16x8*)&As[cur][(wm * 64 + mi * 16 + (l & 15)) * 32 + kc];
#pragma unroll
    for (int ni = 0; ni < 2; ++ni)
      bfr[ni] = *(const bf16x8*)&Bs[cur][(wn * 32 + ni * 16 + (l & 15)) * 32 + kc];
#pragma unroll
    for (int mi = 0; mi < 4; ++mi)
#pragma unroll
      for (int ni = 0; ni < 2; ++ni)
        acc[mi][ni] = __builtin_amdgcn_mfma_f32_16x16x32_bf16(af[mi], bfr[ni], acc[mi][ni], 0, 0, 0);

    __syncthreads();  // drains stage(k+1) vmcnt + guards buf reuse
    cur ^= 1;
  }
#undef STAGE

#pragma unroll
  for (int ni = 0; ni < 2; ++ni) {
    int col = n0 + wn * 32 + ni * 16 + (l & 15);
    float bv_ = bias[col];
    int h = col >> 6, dh = col & 63;
#pragma unroll
    for (int mi = 0; mi < 4; ++mi) {
#pragma unroll
      for (int r = 0; r < 4; ++r) {
        int m = m0 + wm * 64 + mi * 16 + (l >> 4) * 4 + r;
        int b = m >> 11, s = m & 2047;
        unsigned short obf = f2bf(acc[mi][ni][r] + bv_);
        long addr;
        if (!transpose_v)
          addr = ((long)(b * H + h) * S + s) * 64 + dh;
        else
          addr = ((long)(b * H + h) * 64 + dh) * S + s;
        dst[addr] = obf;
      }
    }
  }
}

// ---------------- flash attention v6: v5b + mask restored to LDS smask ----------------
__device__ __forceinline__ void stage_tile(const unsigned short* __restrict__ kb,
                                           const unsigned short* __restrict__ vb,
                                           char* Kb, char* Vb, int kv0, int tid) {
#pragma unroll
  for (int j = 0; j < 2; ++j) {
    int c = tid + j * 256;          // chunk 0..511
    int r = c >> 3;                 // tile row 0..63
    int s = (c & 7) ^ (r & 7);      // inverse-swizzled source slot
    const unsigned short* gk = kb + (kv0 + r) * 64 + s * 8;
    const unsigned short* gv = vb + r * 2048 + kv0 + s * 8;
    __builtin_amdgcn_global_load_lds((const AS1 unsigned int*)gk,
                                     (AS3 unsigned int*)(Kb + c * 16), 16, 0, 0);
    __builtin_amdgcn_global_load_lds((const AS1 unsigned int*)gv,
                                     (AS3 unsigned int*)(Vb + c * 16), 16, 0, 0);
  }
}

__device__ __forceinline__ void compute_tile(const char* Kb, const char* Vb,
                                             const bf16x8 (&qf)[4],
                                             const float* __restrict__ smask,
                                             int kv0, int hi, int qc,
                                             f32x16 (&acco)[2], float& m_run, float& lrow) {
  const float kSc = 0.125f * UNITS;
  const float THR = 8.0f * UNITS;
  const int kx = qc & 7;

  bf16x8 kf[2][4], vf[2][4];
#pragma unroll
  for (int ks = 0; ks < 2; ++ks)
#pragma unroll
    for (int dc = 0; dc < 4; ++dc)
      kf[ks][dc] = *(const bf16x8*)(Kb + (ks * 32 + qc) * 128 + (((dc * 2 + hi) ^ kx) * 16));
#pragma unroll
  for (int dt = 0; dt < 2; ++dt)
#pragma unroll
    for (int c2 = 0; c2 < 4; ++c2)
      vf[dt][c2] = *(const bf16x8*)(Vb + (dt * 32 + qc) * 128 + (((c2 * 2 + hi) ^ kx) * 16));

  f32x16 st0 = {}, st1 = {};
  __builtin_amdgcn_s_setprio(1);
#pragma unroll
  for (int dc = 0; dc < 4; ++dc) {
    st0 = __builtin_amdgcn_mfma_f32_32x32x16_bf16(kf[0][dc], qf[dc], st0, 0, 0, 0);
    st1 = __builtin_amdgcn_mfma_f32_32x32x16_bf16(kf[1][dc], qf[dc], st1, 0, 0, 0);
  }
  __builtin_amdgcn_s_setprio(0);

  // ---- mask add from LDS smask (pre-scaled, broadcast read) ----
  float mf[2][16];
#pragma unroll
  for (int ks = 0; ks < 2; ++ks)
#pragma unroll
    for (int g = 0; g < 4; ++g) {
      float4 t = *(const float4*)&smask[kv0 + ks * 32 + 4 * hi + g * 8];
      mf[ks][g * 4 + 0] = t.x; mf[ks][g * 4 + 1] = t.y;
      mf[ks][g * 4 + 2] = t.z; mf[ks][g * 4 + 3] = t.w;
    }
  float p[2][16];
#pragma unroll
  for (int r = 0; r < 16; ++r) {
    p[0][r] = fmaf(st0[r], kSc, mf[0][r]);
    p[1][r] = fmaf(st1[r], kSc, mf[1][r]);
  }

  float a0 = p[0][0], a1 = p[0][1], a2 = p[0][2], a3 = p[0][3];
#pragma unroll
  for (int r = 4; r < 16; r += 4) {
    a0 = fmaxf(a0, p[0][r]); a1 = fmaxf(a1, p[0][r + 1]);
    a2 = fmaxf(a2, p[0][r + 2]); a3 = fmaxf(a3, p[0][r + 3]);
  }
#pragma unroll
  for (int r = 0; r < 16; r += 4) {
    a0 = fmaxf(a0, p[1][r]); a1 = fmaxf(a1, p[1][r + 1]);
    a2 = fmaxf(a2, p[1][r + 2]); a3 = fmaxf(a3, p[1][r + 3]);
  }
  float pm = fmaxf(fmaxf(a0, a1), fmaxf(a2, a3));
  pm = fmaxf(pm, __shfl_xor(pm, 32));

  if (!__all(pm <= m_run + THR)) {
    float mnew = fmaxf(m_run, pm);
    float scl = EXPF(m_run - mnew);
    lrow *= scl;
#pragma unroll
    for (int dt = 0; dt < 2; ++dt)
#pragma unroll
      for (int r = 0; r < 16; ++r) acco[dt][r] *= scl;
    m_run = mnew;
  }

  float s0 = 0.f, s1 = 0.f, s2 = 0.f, s3 = 0.f;
#pragma unroll
  for (int ks = 0; ks < 2; ++ks)
#pragma unroll
    for (int r = 0; r < 16; r += 4) {
      p[ks][r]     = EXPF(p[ks][r] - m_run);     s0 += p[ks][r];
      p[ks][r + 1] = EXPF(p[ks][r + 1] - m_run); s1 += p[ks][r + 1];
      p[ks][r + 2] = EXPF(p[ks][r + 2] - m_run); s2 += p[ks][r + 2];
      p[ks][r + 3] = EXPF(p[ks][r + 3] - m_run); s3 += p[ks][r + 3];
    }
  float ps = (s0 + s1) + (s2 + s3);
  ps += __shfl_xor(ps, 32);
  lrow += ps;

#pragma unroll
  for (int ks = 0; ks < 2; ++ks) {
    unsigned cp0 = pkbf(p[ks][0], p[ks][1]);
    unsigned cp1 = pkbf(p[ks][2], p[ks][3]);
    unsigned cp2 = pkbf(p[ks][4], p[ks][5]);
    unsigned cp3 = pkbf(p[ks][6], p[ks][7]);
    unsigned cp4 = pkbf(p[ks][8], p[ks][9]);
    unsigned cp5 = pkbf(p[ks][10], p[ks][11]);
    unsigned cp6 = pkbf(p[ks][12], p[ks][13]);
    unsigned cp7 = pkbf(p[ks][14], p[ks][15]);
    asm volatile("v_permlane32_swap_b32 %0, %1" : "+v"(cp0), "+v"(cp2));
    asm volatile("v_permlane32_swap_b32 %0, %1" : "+v"(cp1), "+v"(cp3));
    asm volatile("v_permlane32_swap_b32 %0, %1" : "+v"(cp4), "+v"(cp6));
    asm volatile("v_permlane32_swap_b32 %0, %1" : "+v"(cp5), "+v"(cp7));
    union { unsigned u[4]; bf16x8 v; } B0, B1;
    B0.u[0] = cp0; B0.u[1] = cp1; B0.u[2] = cp2; B0.u[3] = cp3;
    B1.u[0] = cp4; B1.u[1] = cp5; B1.u[2] = cp6; B1.u[3] = cp7;
    __builtin_amdgcn_s_setprio(1);
    acco[0] = __builtin_amdgcn_mfma_f32_32x32x16_bf16(vf[0][ks * 2 + 0], B0.v, acco[0], 0, 0, 0);
    acco[1] = __builtin_amdgcn_mfma_f32_32x32x16_bf16(vf[1][ks * 2 + 0], B0.v, acco[1], 0, 0, 0);
    acco[0] = __builtin_amdgcn_mfma_f32_32x32x16_bf16(vf[0][ks * 2 + 1], B1.v, acco[0], 0, 0, 0);
    acco[1] = __builtin_amdgcn_mfma_f32_32x32x16_bf16(vf[1][ks * 2 + 1], B1.v, acco[1], 0, 0, 0);
    __builtin_amdgcn_s_setprio(0);
  }
}

__global__ __launch_bounds__(256) void attn_kernel(const unsigned short* __restrict__ qh,
                                                   const unsigned short* __restrict__ kh,
                                                   const unsigned short* __restrict__ vt,
                                                   const float* __restrict__ mask,
                                                   float* __restrict__ out) {
  const int S = 2048;
  // XCD swizzle: 1024 blocks; all 16 q-blocks of a bh share an XCD.
  int bid = blockIdx.x;
  int xcd = bid & 7, jj = bid >> 3;
  int bh = xcd * 8 + (jj & 7);
  int qblk = jj >> 3;  // 0..15
  int b = bh >> 4, h = bh & 15;
  int tid = threadIdx.x, l = tid & 63, w = tid >> 6;
  int hi = l >> 5, qc = l & 31;

  const unsigned short* qb = qh + (long)bh * S * 64;
  const unsigned short* kb = kh + (long)bh * S * 64;
  const unsigned short* vb = vt + (long)bh * 64 * S;

  __shared__ float smask[2048];
  // pool: [2][ K(8KB) + V(8KB) ] double buffer = 32 KB; reused as olds[4][16][65]
  __shared__ __align__(16) char pool[32768];
  for (int i = tid; i < S; i += 256)
    smask[i] = (-10000.0f * UNITS) * (1.0f - mask[b * S + i]);

  const int q0 = qblk * 128 + w * 32;

  bf16x8 qf[4];
#pragma unroll
  for (int dc = 0; dc < 4; ++dc)
    qf[dc] = *(const bf16x8*)&qb[(q0 + qc) * 64 + dc * 16 + 8 * hi];

  f32x16 acco[2] = {};
  float m_run = -1e30f, lrow = 0.0f;

  stage_tile(kb, vb, pool, pool + 8192, 0, tid);
  __syncthreads();

  for (int t = 0; t < 32; ++t) {
    char* cur = pool + (t & 1) * 16384;
    if (t < 31) {
      char* nxt = pool + ((t + 1) & 1) * 16384;
      stage_tile(kb, vb, nxt, nxt + 8192, (t + 1) * 64, tid);
    }
    compute_tile(cur, cur + 8192, qf, smask, t * 64, hi, qc, acco, m_run, lrow);
    __syncthreads();
  }

  // ---- epilogue: normalize, per-wave LDS transpose (pool reused), coalesced stores ----
  float (*olds)[16][65] = (float (*)[16][65])pool;
  float linv = 1.0f / lrow;
#pragma unroll
  for (int pass = 0; pass < 2; ++pass) {
    if ((qc >> 4) == pass) {
#pragma unroll
      for (int dt = 0; dt < 2; ++dt)
#pragma unroll
        for (int r = 0; r < 16; ++r) {
          int d = dt * 32 + (r & 3) + 8 * (r >> 2) + 4 * hi;
          olds[w][qc & 15][d] = acco[dt][r] * linv;
        }
    }
    asm volatile("s_waitcnt lgkmcnt(0)" ::: "memory");
#pragma unroll
    for (int r = 0; r < 16; ++r) {
      float val = olds[w][r][l];
      out[((long)b * 2048 + q0 + pass * 16 + r) * 1024 + h * 64 + l] = val;
    }
    asm volatile("s_waitcnt lgkmcnt(0)" ::: "memory");
  }
}

// ---------------- launch ----------------
extern "C" void kernel_launch(void* const* d_in, const int* in_sizes, int n_in,
                              void* d_out, int out_size, void* d_ws, size_t ws_size,
                              hipStream_t stream) {
  const float* q  = (const float*)d_in[0];
  const float* k  = (const float*)d_in[1];
  const float* v  = (const float*)d_in[2];
  const float* mask = (const float*)d_in[3];
  const float* wq = (const float*)d_in[4];
  const float* bq = (const float*)d_in[5];
  const float* wk = (const float*)d_in[6];
  const float* bk = (const float*)d_in[7];
  const float* wv = (const float*)d_in[8];
  const float* bv = (const float*)d_in[9];
  float* out = (float*)d_out;

  char* ws = (char*)d_ws;
  unsigned short* Xq = (unsigned short*)(ws);
  unsigned short* Xk = (unsigned short*)(ws + 16777216L);
  unsigned short* Xv = (unsigned short*)(ws + 33554432L);
  unsigned short* Wq = (unsigned short*)(ws + 50331648L);
  unsigned short* Wk = (unsigned short*)(ws + 52428800L);
  unsigned short* Wv = (unsigned short*)(ws + 54525952L);
  unsigned short* Qh = (unsigned short*)(ws + 56623104L);
  unsigned short* Kh = (unsigned short*)(ws + 73400320L);
  unsigned short* Vt = (unsigned short*)(ws + 90177536L);

  // 1) fused bf16 conversion (1 launch)
  conv_all<<<13824, 256, 0, stream>>>(q, k, v, wq, wk, wv, Xq, Xk, Xv, Wq, Wk, Wv);

  // 2) merged QKV projections (1 launch, 8-wave 2-phase)
  dim3 ggrid(64, 8, 3);
  proj_gemm3<<<ggrid, 512, 0, stream>>>(Xq, Xk, Xv, Wq, Wk, Wv, bq, bk, bv, Qh, Kh, Vt);

  // 3) flash attention + head merge (1 launch, 1024 blocks)
  attn_kernel<<<1024, 256, 0, stream>>>(Qh, Kh, Vt, mask, out);
}